// Round 15
// baseline (135.356 us; speedup 1.0000x reference)
//
#include <hip/hip_runtime.h>
#include <math.h>

#define N_NODES 1024
#define F_DIM   128
#define M_DIM   256
#define E_DIM   8
#define P_PAIRS 523776   // N*(N-1)/2
#define NBLK    2080     // 64*65/2 triangular 16x16 tiles
#define APITCH  33       // padded row pitch in float4 (bank-decorrelating)

typedef float v2f __attribute__((ext_vector_type(2)));

// ---------- Kernel A: pa/pb projections (+cterm folded) + stress; block 256 = BN fold ----------
__global__ __launch_bounds__(256) void kA(const float* __restrict__ x,
                                          const float* __restrict__ ctx,
                                          const float* __restrict__ W1,
                                          const float* __restrict__ b1,
                                          const float* __restrict__ gamma,
                                          const float* __restrict__ beta,
                                          const float* __restrict__ rmean,
                                          const float* __restrict__ rvar,
                                          const float* __restrict__ W2,
                                          const float* __restrict__ b2,
                                          float* __restrict__ pa,
                                          float* __restrict__ pb,
                                          float* __restrict__ stress,
                                          float* __restrict__ w2ft,
                                          float* __restrict__ b2f) {
  const int t = threadIdx.x;

  if (blockIdx.x == 256) {
    __shared__ float bnbs[256];
    const float s   = gamma[t] / sqrtf(rvar[t] + 1e-5f);
    bnbs[t] = beta[t] - s * rmean[t];
    #pragma unroll
    for (int e = 0; e < 8; ++e) w2ft[t * 8 + e] = W2[e * 256 + t] * s;
    __syncthreads();
    const int wv = t >> 6, lane = t & 63;
    #pragma unroll
    for (int r = 0; r < 2; ++r) {
      const int e = wv * 2 + r;
      float acc = 0.f;
      #pragma unroll
      for (int k = 0; k < 4; ++k) acc += W2[e * 256 + lane + 64 * k] * bnbs[lane + 64 * k];
      #pragma unroll
      for (int m = 32; m > 0; m >>= 1) acc += __shfl_xor(acc, m, 64);
      if (lane == 0) b2f[e] = acc + b2[e];
    }
    return;
  }

  __shared__ float xv[4][128];
  const int n0 = blockIdx.x * 4;
  if (t < 128) {
    ((float4*)&xv[0][0])[t] = ((const float4*)(x + (size_t)n0 * F_DIM))[t];
  }
  __syncthreads();

  {
    const int wv = t >> 6, lane = t & 63;
    const float a = xv[wv][lane], b = xv[wv][lane + 64];
    float sum = a + b;
    #pragma unroll
    for (int m = 32; m > 0; m >>= 1) sum += __shfl_xor(sum, m, 64);
    const float mean = sum * (1.0f / 128.0f);
    const float d0 = a - mean, d1 = b - mean;
    float ss = d0 * d0 + d1 * d1;
    #pragma unroll
    for (int m = 32; m > 0; m >>= 1) ss += __shfl_xor(ss, m, 64);
    if (lane == 0) stress[n0 + wv] = sqrtf(ss * (1.0f / 127.0f));
  }

  const float4* wrow = (const float4*)(W1 + (size_t)t * 260);  // W1 row-major [256][260]
  float accA[4] = {0.f, 0.f, 0.f, 0.f};
  float accB[4] = {0.f, 0.f, 0.f, 0.f};
  #pragma unroll 8
  for (int k4 = 0; k4 < 32; ++k4) {
    const float4 wa = wrow[k4];
    const float4 wb = wrow[32 + k4];
    #pragma unroll
    for (int nn = 0; nn < 4; ++nn) {
      const float4 xf = ((const float4*)&xv[nn][0])[k4];
      accA[nn] = fmaf(xf.w, wa.w, fmaf(xf.z, wa.z, fmaf(xf.y, wa.y, fmaf(xf.x, wa.x, accA[nn]))));
      accB[nn] = fmaf(xf.w, wb.w, fmaf(xf.z, wb.z, fmaf(xf.y, wb.y, fmaf(xf.x, wb.x, accB[nn]))));
    }
  }
  const float c0 = ctx[0], c1 = ctx[1], c2 = ctx[2], c3 = ctx[3];
  const float* rowt = W1 + (size_t)t * 260 + 256;
  const float ctv = b1[t] + c0 * rowt[0] + c1 * rowt[1] + c2 * rowt[2] + c3 * rowt[3];
  #pragma unroll
  for (int nn = 0; nn < 4; ++nn) {
    pa[(size_t)(n0 + nn) * M_DIM + t] = accA[nn] + ctv;   // cterm folded (bit-exact)
    pb[(size_t)(n0 + nn) * M_DIM + t] = accB[nn];
  }
}

// ---------- Kernel C: 2080 triangular 16x16 tiles, 256 threads, 1 pair/thread ----------
// R13 structure + bounded staging overlap: chunk-0 loads' latency hidden under
// the stress-mean reduction; chunk-1 loads issued BEFORE compute0 but holding
// only 16 VGPRs (R14 held 32 -> scratch spill, WRITE_SIZE 39MB). Inner loop:
// adjacent-m pairs, v_pk_fma_f32 with op_sel broadcasts of R.lo/R.hi, w via
// s_load SGPR pairs. Per-e chains keep exact m order -> bit-exact. Padded LDS
// rows (pitch 33): staging linear, reads conflict-free.
__global__ __launch_bounds__(256, 8) void kC(const float* __restrict__ pa,
                                             const float* __restrict__ pb,
                                             const float* __restrict__ w2ft,
                                             const float* __restrict__ b2f,
                                             const float* __restrict__ W3,
                                             const float* __restrict__ b3,
                                             const float* __restrict__ stress,
                                             float* __restrict__ out) {
  __shared__ float4 a4[16 * APITCH];   // 16 i-rows, 128-m chunk, pitch 33
  __shared__ float4 b4[16 * APITCH];   // 16 j-rows
  const int t = threadIdx.x;

  // decode p -> (tj, ti): p = tj*(tj+1)/2 + ti, ti <= tj, 64 16-row tiles
  const int p = blockIdx.x;
  int tj = (int)((sqrtf(8.0f * (float)p + 1.0f) - 1.0f) * 0.5f);
  while ((tj + 1) * (tj + 2) / 2 <= p) ++tj;
  while (tj * (tj + 1) / 2 > p) --tj;
  const int ti = p - tj * (tj + 1) / 2;
  const int i0 = ti * 16, j0 = tj * 16;

  const float4* pa4 = (const float4*)pa;
  const float4* pb4 = (const float4*)pb;
  const double* wdp = (const double*)w2ft;   // row m: 4 doubles = e-pairs

  // ---- chunk-0 loads first (latency hidden under stress-mean) ----
  float4 rgA[2], rgB[2];
  #pragma unroll
  for (int q = 0; q < 2; ++q) {
    const int d = q * 256 + t, r = d >> 5, c = d & 31;
    rgA[q] = pa4[(size_t)(i0 + r) * 64 + c];
    rgB[q] = pb4[(size_t)(j0 + r) * 64 + c];
  }

  // ---- stressed-node mean computed UNDER the chunk-0 load latency ----
  float ssum = 0.f;
  {
    const int lane = t & 63;
    #pragma unroll
    for (int k = 0; k < 16; ++k) ssum += stress[lane + 64 * k];
    #pragma unroll
    for (int m = 32; m > 0; m >>= 1) ssum += __shfl_xor(ssum, m, 64);
  }
  const float smean = ssum * (1.0f / 1024.0f);

  const int jx = t & 15;   // j within tile
  const int iy = t >> 4;   // i within tile
  v2f acc[4];              // e-pairs: acc[k] = {acc_e(2k), acc_e(2k+1)}
  #pragma unroll
  for (int k = 0; k < 4; ++k) acc[k] = (v2f){0.f, 0.f};

  const float4* aRow = a4 + iy * APITCH;     // bases hoisted; m4 offsets immediate
  const float4* bRow = b4 + jx * APITCH;

  auto writeTiles = [&]() {
    #pragma unroll
    for (int q = 0; q < 2; ++q) {
      const int d = q * 256 + t, r = d >> 5, c = d & 31;
      a4[r * APITCH + c] = rgA[q];
      b4[r * APITCH + c] = rgB[q];
    }
  };

  auto computeChunk = [&](int cw) {
    #pragma unroll 2
    for (int m4 = 0; m4 < 32; ++m4) {
      const float4 A = aRow[m4];
      const float4 B = bRow[m4];
      const double* wr = wdp + (size_t)(cw + m4) * 16;   // 4 m x 4 e-pair doubles
      const float* Af = (const float*)&A;
      const float* Bf = (const float*)&B;
      #pragma unroll
      for (int g = 0; g < 2; ++g) {        // two adjacent-m groups per m4
        v2f R;
        R.x = fmaxf(Af[2 * g]     + Bf[2 * g],     0.f);   // r for m = 4*m4+2g
        R.y = fmaxf(Af[2 * g + 1] + Bf[2 * g + 1], 0.f);   // r for m = 4*m4+2g+1
        #pragma unroll
        for (int k = 0; k < 4; ++k) {
          const double w0 = wr[(2 * g) * 4 + k];       // {w[m0][2k], w[m0][2k+1]}
          const double w1 = wr[(2 * g + 1) * 4 + k];   // {w[m1][2k], w[m1][2k+1]}
          asm("v_pk_fma_f32 %0, %1, %2, %0 op_sel:[0,0,0] op_sel_hi:[1,0,1]"
              : "+v"(acc[k]) : "s"(w0), "v"(R));
          asm("v_pk_fma_f32 %0, %1, %2, %0 op_sel:[0,1,0] op_sel_hi:[1,1,1]"
              : "+v"(acc[k]) : "s"(w1), "v"(R));
        }
      }
    }
  };

  writeTiles();                  // waits on chunk-0 loads (mostly elapsed)
  __syncthreads();

  // ---- issue chunk-1 loads now; only 16 VGPRs held through compute0 ----
  #pragma unroll
  for (int q = 0; q < 2; ++q) {
    const int d = q * 256 + t, r = d >> 5, c = d & 31;
    rgA[q] = pa4[(size_t)(i0 + r) * 64 + 32 + c];
    rgB[q] = pb4[(size_t)(j0 + r) * 64 + 32 + c];
  }

  computeChunk(0);
  __syncthreads();
  writeTiles();                  // vmcnt long since drained under compute0
  __syncthreads();
  computeChunk(32);

  // ---- epilogue ----
  float w3v[8], b2v[8];
  #pragma unroll
  for (int e = 0; e < 8; ++e) { w3v[e] = W3[e]; b2v[e] = b2f[e]; }
  const float b3v = b3[0];
  const int i = i0 + iy;
  const int j = j0 + jx;
  if (i < j) {
    const float* af = (const float*)&acc[0];
    float logit = b3v;
    #pragma unroll
    for (int e = 0; e < 8; ++e) {
      const float h2 = fmaxf(af[e] + b2v[e], 0.f);
      logit = fmaf(w3v[e], h2, logit);
    }
    const float score = 1.0f / (1.0f + expf(-logit));
    const int idx = i * 1023 - (i * (i - 1)) / 2 + (j - i - 1);
    out[idx] = score;
    const bool mk = (score > 0.5f) && (stress[i] > smean) && (stress[j] > smean);
    out[P_PAIRS + idx] = mk ? 1.0f : 0.0f;
  }
}

extern "C" void kernel_launch(void* const* d_in, const int* in_sizes, int n_in,
                              void* d_out, int out_size, void* d_ws, size_t ws_size,
                              hipStream_t stream) {
  const float* x     = (const float*)d_in[0];
  const float* ctx   = (const float*)d_in[1];
  const float* W1    = (const float*)d_in[2];
  const float* b1    = (const float*)d_in[3];
  const float* gamma = (const float*)d_in[4];
  const float* beta  = (const float*)d_in[5];
  const float* rmean = (const float*)d_in[6];
  const float* rvar  = (const float*)d_in[7];
  const float* W2    = (const float*)d_in[8];
  const float* b2    = (const float*)d_in[9];
  const float* W3    = (const float*)d_in[10];
  const float* b3    = (const float*)d_in[11];
  float* out = (float*)d_out;

  float* ws     = (float*)d_ws;
  float* pa     = ws;              // 1024*256 (cterm pre-folded)
  float* pb     = pa + 262144;     // 1024*256
  float* w2ft   = pb + 262144;     // 256*8 (transposed [m][e], BN-scaled)
  float* b2f    = w2ft + 2048;     // 8
  float* stress = b2f + 8;         // 1024

  hipLaunchKernelGGL(kA, dim3(257), dim3(256), 0, stream, x, ctx, W1, b1, gamma, beta,
                     rmean, rvar, W2, b2, pa, pb, stress, w2ft, b2f);
  hipLaunchKernelGGL(kC, dim3(NBLK), dim3(256), 0, stream, pa, pb, w2ft, b2f,
                     W3, b3, stress, out);
}

// Round 16
// 121.491 us; speedup vs baseline: 1.1141x; 1.1141x over previous
//
#include <hip/hip_runtime.h>
#include <math.h>

#define N_NODES 1024
#define F_DIM   128
#define M_DIM   256
#define E_DIM   8
#define P_PAIRS 523776   // N*(N-1)/2
#define NBLK    2080     // 64*65/2 triangular 16x16 tiles
#define APITCH  33       // padded row pitch in float4 (bank-decorrelating)

typedef float v2f __attribute__((ext_vector_type(2)));

// ---------- Kernel A: pa/pb projections (+cterm folded) + stress; block 256 = BN fold ----------
__global__ __launch_bounds__(256) void kA(const float* __restrict__ x,
                                          const float* __restrict__ ctx,
                                          const float* __restrict__ W1,
                                          const float* __restrict__ b1,
                                          const float* __restrict__ gamma,
                                          const float* __restrict__ beta,
                                          const float* __restrict__ rmean,
                                          const float* __restrict__ rvar,
                                          const float* __restrict__ W2,
                                          const float* __restrict__ b2,
                                          float* __restrict__ pa,
                                          float* __restrict__ pb,
                                          float* __restrict__ stress,
                                          float* __restrict__ w2ft,
                                          float* __restrict__ b2f) {
  const int t = threadIdx.x;

  if (blockIdx.x == 256) {
    __shared__ float bnbs[256];
    const float s   = gamma[t] / sqrtf(rvar[t] + 1e-5f);
    bnbs[t] = beta[t] - s * rmean[t];
    #pragma unroll
    for (int e = 0; e < 8; ++e) w2ft[t * 8 + e] = W2[e * 256 + t] * s;
    __syncthreads();
    const int wv = t >> 6, lane = t & 63;
    #pragma unroll
    for (int r = 0; r < 2; ++r) {
      const int e = wv * 2 + r;
      float acc = 0.f;
      #pragma unroll
      for (int k = 0; k < 4; ++k) acc += W2[e * 256 + lane + 64 * k] * bnbs[lane + 64 * k];
      #pragma unroll
      for (int m = 32; m > 0; m >>= 1) acc += __shfl_xor(acc, m, 64);
      if (lane == 0) b2f[e] = acc + b2[e];
    }
    return;
  }

  __shared__ float xv[4][128];
  const int n0 = blockIdx.x * 4;
  if (t < 128) {
    ((float4*)&xv[0][0])[t] = ((const float4*)(x + (size_t)n0 * F_DIM))[t];
  }
  __syncthreads();

  {
    const int wv = t >> 6, lane = t & 63;
    const float a = xv[wv][lane], b = xv[wv][lane + 64];
    float sum = a + b;
    #pragma unroll
    for (int m = 32; m > 0; m >>= 1) sum += __shfl_xor(sum, m, 64);
    const float mean = sum * (1.0f / 128.0f);
    const float d0 = a - mean, d1 = b - mean;
    float ss = d0 * d0 + d1 * d1;
    #pragma unroll
    for (int m = 32; m > 0; m >>= 1) ss += __shfl_xor(ss, m, 64);
    if (lane == 0) stress[n0 + wv] = sqrtf(ss * (1.0f / 127.0f));
  }

  const float4* wrow = (const float4*)(W1 + (size_t)t * 260);  // W1 row-major [256][260]
  float accA[4] = {0.f, 0.f, 0.f, 0.f};
  float accB[4] = {0.f, 0.f, 0.f, 0.f};
  #pragma unroll 8
  for (int k4 = 0; k4 < 32; ++k4) {
    const float4 wa = wrow[k4];
    const float4 wb = wrow[32 + k4];
    #pragma unroll
    for (int nn = 0; nn < 4; ++nn) {
      const float4 xf = ((const float4*)&xv[nn][0])[k4];
      accA[nn] = fmaf(xf.w, wa.w, fmaf(xf.z, wa.z, fmaf(xf.y, wa.y, fmaf(xf.x, wa.x, accA[nn]))));
      accB[nn] = fmaf(xf.w, wb.w, fmaf(xf.z, wb.z, fmaf(xf.y, wb.y, fmaf(xf.x, wb.x, accB[nn]))));
    }
  }
  const float c0 = ctx[0], c1 = ctx[1], c2 = ctx[2], c3 = ctx[3];
  const float* rowt = W1 + (size_t)t * 260 + 256;
  const float ctv = b1[t] + c0 * rowt[0] + c1 * rowt[1] + c2 * rowt[2] + c3 * rowt[3];
  #pragma unroll
  for (int nn = 0; nn < 4; ++nn) {
    pa[(size_t)(n0 + nn) * M_DIM + t] = accA[nn] + ctv;   // cterm folded (bit-exact)
    pb[(size_t)(n0 + nn) * M_DIM + t] = accB[nn];
  }
}

// ---------- Kernel C: 2080 triangular 16x16 tiles, 256 threads, 1 pair/thread ----------
// SINGLE-BARRIER LDS double-buffer: both 128-m chunks loaded up front (latency
// hidden under the stress-mean reduction), both LDS buffers written immediately
// (no registers live across compute -> no spill; R14/R15's failure), ONE
// __syncthreads, then both chunks computed back-to-back with no further barrier.
// LDS 33.8 KB -> 4 blocks/CU; launch_bounds(256,4) -> VGPR cap 128. Inner loop
// identical to R13: adjacent-m pairs, v_pk_fma_f32 op_sel broadcasts, w via
// s_load SGPR pairs; per-e chains keep exact m order -> bit-exact.
__global__ __launch_bounds__(256, 4) void kC(const float* __restrict__ pa,
                                             const float* __restrict__ pb,
                                             const float* __restrict__ w2ft,
                                             const float* __restrict__ b2f,
                                             const float* __restrict__ W3,
                                             const float* __restrict__ b3,
                                             const float* __restrict__ stress,
                                             float* __restrict__ out) {
  __shared__ float4 a4[2][16 * APITCH];   // [chunk][16 i-rows x pitch 33]
  __shared__ float4 b4[2][16 * APITCH];   // [chunk][16 j-rows x pitch 33]
  const int t = threadIdx.x;

  // decode p -> (tj, ti): p = tj*(tj+1)/2 + ti, ti <= tj, 64 16-row tiles
  const int p = blockIdx.x;
  int tj = (int)((sqrtf(8.0f * (float)p + 1.0f) - 1.0f) * 0.5f);
  while ((tj + 1) * (tj + 2) / 2 <= p) ++tj;
  while (tj * (tj + 1) / 2 > p) --tj;
  const int ti = p - tj * (tj + 1) / 2;
  const int i0 = ti * 16, j0 = tj * 16;

  const float4* pa4 = (const float4*)pa;
  const float4* pb4 = (const float4*)pb;
  const double* wdp = (const double*)w2ft;   // row m: 4 doubles = e-pairs

  // ---- issue ALL staging loads (both chunks, 8 float4 on vmcnt) ----
  float4 rA[2][2], rB[2][2];
  #pragma unroll
  for (int cb = 0; cb < 2; ++cb) {
    #pragma unroll
    for (int q = 0; q < 2; ++q) {
      const int d = q * 256 + t, r = d >> 5, c = d & 31;
      rA[cb][q] = pa4[(size_t)(i0 + r) * 64 + cb * 32 + c];
      rB[cb][q] = pb4[(size_t)(j0 + r) * 64 + cb * 32 + c];
    }
  }

  // ---- stressed-node mean computed UNDER the staging-load latency ----
  float ssum = 0.f;
  {
    const int lane = t & 63;
    #pragma unroll
    for (int k = 0; k < 16; ++k) ssum += stress[lane + 64 * k];
    #pragma unroll
    for (int m = 32; m > 0; m >>= 1) ssum += __shfl_xor(ssum, m, 64);
  }
  const float smean = ssum * (1.0f / 1024.0f);

  // ---- write BOTH buffers now (no liveness across compute) ----
  #pragma unroll
  for (int cb = 0; cb < 2; ++cb) {
    #pragma unroll
    for (int q = 0; q < 2; ++q) {
      const int d = q * 256 + t, r = d >> 5, c = d & 31;
      a4[cb][r * APITCH + c] = rA[cb][q];
      b4[cb][r * APITCH + c] = rB[cb][q];
    }
  }
  __syncthreads();   // the ONLY barrier

  const int jx = t & 15;   // j within tile
  const int iy = t >> 4;   // i within tile
  v2f acc[4];              // e-pairs: acc[k] = {acc_e(2k), acc_e(2k+1)}
  #pragma unroll
  for (int k = 0; k < 4; ++k) acc[k] = (v2f){0.f, 0.f};

  #pragma unroll
  for (int cb = 0; cb < 2; ++cb) {
    const float4* aRow = &a4[cb][iy * APITCH];   // bases hoisted; m4 offsets immediate
    const float4* bRow = &b4[cb][jx * APITCH];
    const int cw = cb * 32;
    #pragma unroll 2
    for (int m4 = 0; m4 < 32; ++m4) {
      const float4 A = aRow[m4];
      const float4 B = bRow[m4];
      const double* wr = wdp + (size_t)(cw + m4) * 16;   // 4 m x 4 e-pair doubles
      const float* Af = (const float*)&A;
      const float* Bf = (const float*)&B;
      #pragma unroll
      for (int g = 0; g < 2; ++g) {        // two adjacent-m groups per m4
        v2f R;
        R.x = fmaxf(Af[2 * g]     + Bf[2 * g],     0.f);   // r for m = 4*m4+2g
        R.y = fmaxf(Af[2 * g + 1] + Bf[2 * g + 1], 0.f);   // r for m = 4*m4+2g+1
        #pragma unroll
        for (int k = 0; k < 4; ++k) {
          const double w0 = wr[(2 * g) * 4 + k];       // {w[m0][2k], w[m0][2k+1]}
          const double w1 = wr[(2 * g + 1) * 4 + k];   // {w[m1][2k], w[m1][2k+1]}
          asm("v_pk_fma_f32 %0, %1, %2, %0 op_sel:[0,0,0] op_sel_hi:[1,0,1]"
              : "+v"(acc[k]) : "s"(w0), "v"(R));
          asm("v_pk_fma_f32 %0, %1, %2, %0 op_sel:[0,1,0] op_sel_hi:[1,1,1]"
              : "+v"(acc[k]) : "s"(w1), "v"(R));
        }
      }
    }
  }

  // ---- epilogue ----
  float w3v[8], b2v[8];
  #pragma unroll
  for (int e = 0; e < 8; ++e) { w3v[e] = W3[e]; b2v[e] = b2f[e]; }
  const float b3v = b3[0];
  const int i = i0 + iy;
  const int j = j0 + jx;
  if (i < j) {
    const float* af = (const float*)&acc[0];
    float logit = b3v;
    #pragma unroll
    for (int e = 0; e < 8; ++e) {
      const float h2 = fmaxf(af[e] + b2v[e], 0.f);
      logit = fmaf(w3v[e], h2, logit);
    }
    const float score = 1.0f / (1.0f + expf(-logit));
    const int idx = i * 1023 - (i * (i - 1)) / 2 + (j - i - 1);
    out[idx] = score;
    const bool mk = (score > 0.5f) && (stress[i] > smean) && (stress[j] > smean);
    out[P_PAIRS + idx] = mk ? 1.0f : 0.0f;
  }
}

extern "C" void kernel_launch(void* const* d_in, const int* in_sizes, int n_in,
                              void* d_out, int out_size, void* d_ws, size_t ws_size,
                              hipStream_t stream) {
  const float* x     = (const float*)d_in[0];
  const float* ctx   = (const float*)d_in[1];
  const float* W1    = (const float*)d_in[2];
  const float* b1    = (const float*)d_in[3];
  const float* gamma = (const float*)d_in[4];
  const float* beta  = (const float*)d_in[5];
  const float* rmean = (const float*)d_in[6];
  const float* rvar  = (const float*)d_in[7];
  const float* W2    = (const float*)d_in[8];
  const float* b2    = (const float*)d_in[9];
  const float* W3    = (const float*)d_in[10];
  const float* b3    = (const float*)d_in[11];
  float* out = (float*)d_out;

  float* ws     = (float*)d_ws;
  float* pa     = ws;              // 1024*256 (cterm pre-folded)
  float* pb     = pa + 262144;     // 1024*256
  float* w2ft   = pb + 262144;     // 256*8 (transposed [m][e], BN-scaled)
  float* b2f    = w2ft + 2048;     // 8
  float* stress = b2f + 8;         // 1024

  hipLaunchKernelGGL(kA, dim3(257), dim3(256), 0, stream, x, ctx, W1, b1, gamma, beta,
                     rmean, rvar, W2, b2, pa, pb, stress, w2ft, b2f);
  hipLaunchKernelGGL(kC, dim3(NBLK), dim3(256), 0, stream, pa, pb, w2ft, b2f,
                     W3, b3, stress, out);
}

// Round 17
// 119.432 us; speedup vs baseline: 1.1333x; 1.0172x over previous
//
#include <hip/hip_runtime.h>
#include <math.h>

#define N_NODES 1024
#define F_DIM   128
#define M_DIM   256
#define E_DIM   8
#define P_PAIRS 523776   // N*(N-1)/2
#define NBLK    1056     // sum_{tj=0..31} (2*tj+2) 16x32 tiles
#define APITCH  33       // padded row pitch in float4 (bank-decorrelating)

typedef float v2f __attribute__((ext_vector_type(2)));

// ---------- Kernel A: pa/pb projections (+cterm folded) + stress; block 256 = BN fold ----------
__global__ __launch_bounds__(256) void kA(const float* __restrict__ x,
                                          const float* __restrict__ ctx,
                                          const float* __restrict__ W1,
                                          const float* __restrict__ b1,
                                          const float* __restrict__ gamma,
                                          const float* __restrict__ beta,
                                          const float* __restrict__ rmean,
                                          const float* __restrict__ rvar,
                                          const float* __restrict__ W2,
                                          const float* __restrict__ b2,
                                          float* __restrict__ pa,
                                          float* __restrict__ pb,
                                          float* __restrict__ stress,
                                          float* __restrict__ w2ft,
                                          float* __restrict__ b2f) {
  const int t = threadIdx.x;

  if (blockIdx.x == 256) {
    __shared__ float bnbs[256];
    const float s   = gamma[t] / sqrtf(rvar[t] + 1e-5f);
    bnbs[t] = beta[t] - s * rmean[t];
    #pragma unroll
    for (int e = 0; e < 8; ++e) w2ft[t * 8 + e] = W2[e * 256 + t] * s;
    __syncthreads();
    const int wv = t >> 6, lane = t & 63;
    #pragma unroll
    for (int r = 0; r < 2; ++r) {
      const int e = wv * 2 + r;
      float acc = 0.f;
      #pragma unroll
      for (int k = 0; k < 4; ++k) acc += W2[e * 256 + lane + 64 * k] * bnbs[lane + 64 * k];
      #pragma unroll
      for (int m = 32; m > 0; m >>= 1) acc += __shfl_xor(acc, m, 64);
      if (lane == 0) b2f[e] = acc + b2[e];
    }
    return;
  }

  __shared__ float xv[4][128];
  const int n0 = blockIdx.x * 4;
  if (t < 128) {
    ((float4*)&xv[0][0])[t] = ((const float4*)(x + (size_t)n0 * F_DIM))[t];
  }
  __syncthreads();

  {
    const int wv = t >> 6, lane = t & 63;
    const float a = xv[wv][lane], b = xv[wv][lane + 64];
    float sum = a + b;
    #pragma unroll
    for (int m = 32; m > 0; m >>= 1) sum += __shfl_xor(sum, m, 64);
    const float mean = sum * (1.0f / 128.0f);
    const float d0 = a - mean, d1 = b - mean;
    float ss = d0 * d0 + d1 * d1;
    #pragma unroll
    for (int m = 32; m > 0; m >>= 1) ss += __shfl_xor(ss, m, 64);
    if (lane == 0) stress[n0 + wv] = sqrtf(ss * (1.0f / 127.0f));
  }

  const float4* wrow = (const float4*)(W1 + (size_t)t * 260);  // W1 row-major [256][260]
  float accA[4] = {0.f, 0.f, 0.f, 0.f};
  float accB[4] = {0.f, 0.f, 0.f, 0.f};
  #pragma unroll 8
  for (int k4 = 0; k4 < 32; ++k4) {
    const float4 wa = wrow[k4];
    const float4 wb = wrow[32 + k4];
    #pragma unroll
    for (int nn = 0; nn < 4; ++nn) {
      const float4 xf = ((const float4*)&xv[nn][0])[k4];
      accA[nn] = fmaf(xf.w, wa.w, fmaf(xf.z, wa.z, fmaf(xf.y, wa.y, fmaf(xf.x, wa.x, accA[nn]))));
      accB[nn] = fmaf(xf.w, wb.w, fmaf(xf.z, wb.z, fmaf(xf.y, wb.y, fmaf(xf.x, wb.x, accB[nn]))));
    }
  }
  const float c0 = ctx[0], c1 = ctx[1], c2 = ctx[2], c3 = ctx[3];
  const float* rowt = W1 + (size_t)t * 260 + 256;
  const float ctv = b1[t] + c0 * rowt[0] + c1 * rowt[1] + c2 * rowt[2] + c3 * rowt[3];
  #pragma unroll
  for (int nn = 0; nn < 4; ++nn) {
    pa[(size_t)(n0 + nn) * M_DIM + t] = accA[nn] + ctv;   // cterm folded (bit-exact)
    pb[(size_t)(n0 + nn) * M_DIM + t] = accB[nn];
  }
}

// ---------- Kernel C: 1056 triangular 16x32 tiles, 256 threads, 2 pairs/thread ----------
// j-packed micro-tile: pairs (i, jx) and (i, jx+16) share ONE A-row ds_read ->
// 1.5 b128/pair (vs 2) -- the LDS pipe was the binding resource (R16 model:
// 384 cy LDS demand vs 192 cy VALU per m4-round -> 50% util, matches counters).
// acc[e] = {acc_j0[e], acc_j1[e]} (R9's proven packing): R = {r_j0, r_j1},
// w e-pair in an SGPR double, op_sel broadcasts w.lo / w.hi (R9 asm verbatim,
// compiled + absmax 0). Per-e/per-j chains keep exact m order -> bit-exact.
// Chunked serial staging, transient regs only (no spill), 25.3 KB LDS.
__global__ __launch_bounds__(256, 6) void kC(const float* __restrict__ pa,
                                             const float* __restrict__ pb,
                                             const float* __restrict__ w2ft,
                                             const float* __restrict__ b2f,
                                             const float* __restrict__ W3,
                                             const float* __restrict__ b3,
                                             const float* __restrict__ stress,
                                             float* __restrict__ out) {
  __shared__ float4 a4[16 * APITCH];   // 16 i-rows, 128-m chunk, pitch 33
  __shared__ float4 b4[32 * APITCH];   // 32 j-rows
  const int t = threadIdx.x;

  // decode p -> (tj, si): p = tj*(tj+1) + si, si in [0, 2*tj+2)
  const int p = blockIdx.x;
  int tj = (int)((sqrtf(4.0f * (float)p + 1.0f) - 1.0f) * 0.5f);
  while ((tj + 1) * (tj + 2) <= p) ++tj;
  while (tj * (tj + 1) > p) --tj;
  const int si = p - tj * (tj + 1);
  const int i0 = si * 16, j0 = tj * 32;

  const float4* pa4 = (const float4*)pa;
  const float4* pb4 = (const float4*)pb;
  const double* wdp = (const double*)w2ft;   // row m: 4 doubles = e-pairs

  // ---- chunk-0 staging loads issued; stress-mean computed under their latency ----
  float4 rA[2], rB[4];
  #pragma unroll
  for (int q = 0; q < 2; ++q) {
    const int d = q * 256 + t, r = d >> 5, c = d & 31;
    rA[q] = pa4[(size_t)(i0 + r) * 64 + c];
  }
  #pragma unroll
  for (int q = 0; q < 4; ++q) {
    const int d = q * 256 + t, r = d >> 5, c = d & 31;
    rB[q] = pb4[(size_t)(j0 + r) * 64 + c];
  }

  float ssum = 0.f;
  {
    const int lane = t & 63;
    #pragma unroll
    for (int k = 0; k < 16; ++k) ssum += stress[lane + 64 * k];
    #pragma unroll
    for (int m = 32; m > 0; m >>= 1) ssum += __shfl_xor(ssum, m, 64);
  }
  const float smean = ssum * (1.0f / 1024.0f);

  // ---- write chunk-0 tiles (transient regs die here; no spill risk) ----
  #pragma unroll
  for (int q = 0; q < 2; ++q) {
    const int d = q * 256 + t, r = d >> 5, c = d & 31;
    a4[r * APITCH + c] = rA[q];
  }
  #pragma unroll
  for (int q = 0; q < 4; ++q) {
    const int d = q * 256 + t, r = d >> 5, c = d & 31;
    b4[r * APITCH + c] = rB[q];
  }
  __syncthreads();

  const int jx = t & 15;   // j pair: jx, jx+16
  const int iy = t >> 4;   // i within tile, 0..15
  v2f acc[8];              // per e: {acc for j=jx, acc for j=jx+16}
  #pragma unroll
  for (int e = 0; e < 8; ++e) acc[e] = (v2f){0.f, 0.f};

  const float4* aRow  = a4 + iy * APITCH;          // bases hoisted; m4 offsets immediate
  const float4* bRow0 = b4 + jx * APITCH;
  const float4* bRow1 = b4 + (jx + 16) * APITCH;

  auto computeChunk = [&](int cw) {
    #pragma unroll 2
    for (int m4 = 0; m4 < 32; ++m4) {
      const float4 A  = aRow[m4];
      const float4 B0 = bRow0[m4];
      const float4 B1 = bRow1[m4];
      const double* wr = wdp + (size_t)(cw + m4) * 16;   // 4 m x 4 e-pair doubles
      const float* Af  = (const float*)&A;
      const float* B0f = (const float*)&B0;
      const float* B1f = (const float*)&B1;
      #pragma unroll
      for (int mm = 0; mm < 4; ++mm) {
        v2f R;
        R.x = fmaxf(Af[mm] + B0f[mm], 0.f);   // r for (i, jx)
        R.y = fmaxf(Af[mm] + B1f[mm], 0.f);   // r for (i, jx+16)
        #pragma unroll
        for (int k = 0; k < 4; ++k) {
          const double wp = wr[mm * 4 + k];   // {w[m][2k], w[m][2k+1]} in SGPR pair
          // even e = 2k: broadcast LO word of wp to both halves (R9-proven form)
          asm("v_pk_fma_f32 %0, %1, %2, %0 op_sel:[0,0,0] op_sel_hi:[0,1,1]"
              : "+v"(acc[2 * k]) : "s"(wp), "v"(R));
          // odd e = 2k+1: broadcast HI word of wp to both halves
          asm("v_pk_fma_f32 %0, %1, %2, %0 op_sel:[1,0,0] op_sel_hi:[1,1,1]"
              : "+v"(acc[2 * k + 1]) : "s"(wp), "v"(R));
        }
      }
    }
  };

  computeChunk(0);
  __syncthreads();

  // ---- stage chunk 1 (transient regs again) ----
  #pragma unroll
  for (int q = 0; q < 2; ++q) {
    const int d = q * 256 + t, r = d >> 5, c = d & 31;
    rA[q] = pa4[(size_t)(i0 + r) * 64 + 32 + c];
  }
  #pragma unroll
  for (int q = 0; q < 4; ++q) {
    const int d = q * 256 + t, r = d >> 5, c = d & 31;
    rB[q] = pb4[(size_t)(j0 + r) * 64 + 32 + c];
  }
  #pragma unroll
  for (int q = 0; q < 2; ++q) {
    const int d = q * 256 + t, r = d >> 5, c = d & 31;
    a4[r * APITCH + c] = rA[q];
  }
  #pragma unroll
  for (int q = 0; q < 4; ++q) {
    const int d = q * 256 + t, r = d >> 5, c = d & 31;
    b4[r * APITCH + c] = rB[q];
  }
  __syncthreads();

  computeChunk(32);

  // ---- epilogue ----
  float w3v[8], b2v[8];
  #pragma unroll
  for (int e = 0; e < 8; ++e) { w3v[e] = W3[e]; b2v[e] = b2f[e]; }
  const float b3v = b3[0];
  const int i = i0 + iy;
  #pragma unroll
  for (int jb = 0; jb < 2; ++jb) {
    const int j = j0 + jx + jb * 16;
    if (i < j) {
      float logit = b3v;
      #pragma unroll
      for (int e = 0; e < 8; ++e) {
        const float av = jb ? acc[e].y : acc[e].x;
        const float h2 = fmaxf(av + b2v[e], 0.f);
        logit = fmaf(w3v[e], h2, logit);
      }
      const float score = 1.0f / (1.0f + expf(-logit));
      const int idx = i * 1023 - (i * (i - 1)) / 2 + (j - i - 1);
      out[idx] = score;
      const bool mk = (score > 0.5f) && (stress[i] > smean) && (stress[j] > smean);
      out[P_PAIRS + idx] = mk ? 1.0f : 0.0f;
    }
  }
}

extern "C" void kernel_launch(void* const* d_in, const int* in_sizes, int n_in,
                              void* d_out, int out_size, void* d_ws, size_t ws_size,
                              hipStream_t stream) {
  const float* x     = (const float*)d_in[0];
  const float* ctx   = (const float*)d_in[1];
  const float* W1    = (const float*)d_in[2];
  const float* b1    = (const float*)d_in[3];
  const float* gamma = (const float*)d_in[4];
  const float* beta  = (const float*)d_in[5];
  const float* rmean = (const float*)d_in[6];
  const float* rvar  = (const float*)d_in[7];
  const float* W2    = (const float*)d_in[8];
  const float* b2    = (const float*)d_in[9];
  const float* W3    = (const float*)d_in[10];
  const float* b3    = (const float*)d_in[11];
  float* out = (float*)d_out;

  float* ws     = (float*)d_ws;
  float* pa     = ws;              // 1024*256 (cterm pre-folded)
  float* pb     = pa + 262144;     // 1024*256
  float* w2ft   = pb + 262144;     // 256*8 (transposed [m][e], BN-scaled)
  float* b2f    = w2ft + 2048;     // 8
  float* stress = b2f + 8;         // 1024

  hipLaunchKernelGGL(kA, dim3(257), dim3(256), 0, stream, x, ctx, W1, b1, gamma, beta,
                     rmean, rvar, W2, b2, pa, pb, stress, w2ft, b2f);
  hipLaunchKernelGGL(kC, dim3(NBLK), dim3(256), 0, stream, pa, pb, w2ft, b2f,
                     W3, b3, stress, out);
}